// Round 2
// baseline (11518.167 us; speedup 1.0000x reference)
//
#include <hip/hip_runtime.h>
#include <math.h>

#define NN 100000
#define CC 256
#define EE 3200000

// ---------------- degree / dinv ----------------

__global__ __launch_bounds__(256) void k_init_deg(float* __restrict__ deg) {
    int i = blockIdx.x * 256 + threadIdx.x;
    if (i < NN) deg[i] = 1.0f;  // self-loop contribution
}

__global__ __launch_bounds__(256) void k_count_deg(const int* __restrict__ col,
                                                   float* __restrict__ deg) {
    int e = blockIdx.x * 256 + threadIdx.x;
    if (e < EE) atomicAdd(&deg[col[e]], 1.0f);
}

__global__ __launch_bounds__(256) void k_rsqrt(float* __restrict__ deg) {
    int i = blockIdx.x * 256 + threadIdx.x;
    if (i < NN) deg[i] = rsqrtf(deg[i]);  // deg >= 1 always
}

// ---------------- fp32 NT GEMM: C[i][j] = sum_k A[i][k] * B[j][k] (+bias, relu) ----------------
// A: [M,K] row-major, B: [Nc,K] row-major. BM=BN=64, BK=32, 256 threads, 4x4 per thread.

__global__ __launch_bounds__(256) void k_gemm_nt(const float* __restrict__ A,
                                                 const float* __restrict__ B,
                                                 const float* __restrict__ bias,
                                                 float* __restrict__ Cout,
                                                 int M, int Nc, int K, int do_relu) {
    __shared__ float As[64][33];
    __shared__ float Bs[64][33];
    const int bm = blockIdx.y * 64;
    const int bn = blockIdx.x * 64;
    const int tid = threadIdx.x;
    const int tx = tid & 15;   // col group
    const int ty = tid >> 4;   // row group

    float acc[4][4] = {};

    for (int k0 = 0; k0 < K; k0 += 32) {
        // load 64x32 tiles, 512 float4 total, 2 per thread
        #pragma unroll
        for (int r = 0; r < 2; ++r) {
            int idx = tid + r * 256;        // 0..511
            int row = idx >> 3;             // 0..63
            int c4  = (idx & 7) * 4;        // 0..28
            int grow = bm + row;
            float4 va = make_float4(0.f, 0.f, 0.f, 0.f);
            if (grow < M) va = *(const float4*)&A[(size_t)grow * K + k0 + c4];
            As[row][c4 + 0] = va.x; As[row][c4 + 1] = va.y;
            As[row][c4 + 2] = va.z; As[row][c4 + 3] = va.w;
            int brow = bn + row;
            float4 vb = make_float4(0.f, 0.f, 0.f, 0.f);
            if (brow < Nc) vb = *(const float4*)&B[(size_t)brow * K + k0 + c4];
            Bs[row][c4 + 0] = vb.x; Bs[row][c4 + 1] = vb.y;
            Bs[row][c4 + 2] = vb.z; Bs[row][c4 + 3] = vb.w;
        }
        __syncthreads();
        #pragma unroll
        for (int kk = 0; kk < 32; ++kk) {
            float a[4], b[4];
            #pragma unroll
            for (int r = 0; r < 4; ++r) a[r] = As[ty * 4 + r][kk];
            #pragma unroll
            for (int c = 0; c < 4; ++c) b[c] = Bs[tx * 4 + c][kk];
            #pragma unroll
            for (int r = 0; r < 4; ++r)
                #pragma unroll
                for (int c = 0; c < 4; ++c)
                    acc[r][c] = fmaf(a[r], b[c], acc[r][c]);
        }
        __syncthreads();
    }

    #pragma unroll
    for (int r = 0; r < 4; ++r) {
        int grow = bm + ty * 4 + r;
        if (grow >= M) continue;
        int gcol = bn + tx * 4;
        float4 v;
        v.x = acc[r][0]; v.y = acc[r][1]; v.z = acc[r][2]; v.w = acc[r][3];
        if (bias) {
            v.x += bias[gcol + 0]; v.y += bias[gcol + 1];
            v.z += bias[gcol + 2]; v.w += bias[gcol + 3];
        }
        if (do_relu) {
            v.x = fmaxf(v.x, 0.f); v.y = fmaxf(v.y, 0.f);
            v.z = fmaxf(v.z, 0.f); v.w = fmaxf(v.w, 0.f);
        }
        *(float4*)&Cout[(size_t)grow * Nc + gcol] = v;
    }
}

// ---------------- aggregation ----------------

// agg[i][:] = dinv[i]^2 * h[i][:]   (self-loop term; also initializes agg)
__global__ __launch_bounds__(256) void k_self_loop(const float* __restrict__ dinv,
                                                   const float* __restrict__ h,
                                                   float* __restrict__ agg) {
    size_t idx = (size_t)blockIdx.x * 256 + threadIdx.x;  // float4 index
    if (idx >= (size_t)NN * (CC / 4)) return;
    int node = (int)(idx >> 6);  // CC/4 = 64 float4 per node
    float s = dinv[node];
    s = s * s;
    float4 v = ((const float4*)h)[idx];
    float4 o;
    o.x = v.x * s; o.y = v.y * s; o.z = v.z * s; o.w = v.w * s;
    ((float4*)agg)[idx] = o;
}

// one wave per edge: agg[col] += h[row] * dinv[row]*dinv[col]
__global__ __launch_bounds__(256) void k_edge_agg(const int* __restrict__ rowi,
                                                  const int* __restrict__ coli,
                                                  const float* __restrict__ dinv,
                                                  const float* __restrict__ h,
                                                  float* __restrict__ agg) {
    int e = blockIdx.x * 4 + (threadIdx.x >> 6);
    if (e >= EE) return;
    int lane = threadIdx.x & 63;
    int r = rowi[e];
    int c = coli[e];
    float norm = dinv[r] * dinv[c];
    float4 v = ((const float4*)&h[(size_t)r * CC])[lane];
    float* dst = &agg[(size_t)c * CC + lane * 4];
    atomicAdd(dst + 0, v.x * norm);
    atomicAdd(dst + 1, v.y * norm);
    atomicAdd(dst + 2, v.z * norm);
    atomicAdd(dst + 3, v.w * norm);
}

// h1 = relu(agg + b_gcn)
__global__ __launch_bounds__(256) void k_bias_relu(const float* __restrict__ agg,
                                                   const float* __restrict__ bias,
                                                   float* __restrict__ h1) {
    size_t idx = (size_t)blockIdx.x * 256 + threadIdx.x;  // float4 index
    if (idx >= (size_t)NN * (CC / 4)) return;
    int c4 = (int)(idx & 63);
    float4 v = ((const float4*)agg)[idx];
    float4 b = ((const float4*)bias)[c4];
    float4 o;
    o.x = fmaxf(v.x + b.x, 0.f);
    o.y = fmaxf(v.y + b.y, 0.f);
    o.z = fmaxf(v.z + b.z, 0.f);
    o.w = fmaxf(v.w + b.w, 0.f);
    ((float4*)h1)[idx] = o;
}

// ---------------- final layer: out = sigmoid(relu(h2 @ W2.T + b2)) ----------------

__global__ __launch_bounds__(256) void k_final(const float* __restrict__ h2,
                                               const float* __restrict__ W2,
                                               const float* __restrict__ b2,
                                               float* __restrict__ out) {
    int wid = threadIdx.x >> 6;
    int lane = threadIdx.x & 63;
    int rowi = blockIdx.x * 4 + wid;
    if (rowi >= NN) return;
    float4 a = ((const float4*)&h2[(size_t)rowi * CC])[lane];
    float4 w = ((const float4*)W2)[lane];
    float s = a.x * w.x + a.y * w.y + a.z * w.z + a.w * w.w;
    #pragma unroll
    for (int off = 32; off >= 1; off >>= 1) s += __shfl_down(s, off, 64);
    if (lane == 0) {
        float z = s + b2[0];
        z = fmaxf(z, 0.f);
        out[rowi] = 1.0f / (1.0f + expf(-z));
    }
}

// ---------------- launcher ----------------

extern "C" void kernel_launch(void* const* d_in, const int* in_sizes, int n_in,
                              void* d_out, int out_size, void* d_ws, size_t ws_size,
                              hipStream_t stream) {
    const float* x     = (const float*)d_in[0];   // [N,C]
    const int*   eidx  = (const int*)d_in[1];     // [2,E]
    const float* W_gcn = (const float*)d_in[2];   // [C,C]
    const float* b_gcn = (const float*)d_in[3];   // [C]
    const float* W1    = (const float*)d_in[4];   // [C,C]
    const float* b1    = (const float*)d_in[5];   // [C]
    const float* W2    = (const float*)d_in[6];   // [1,C]
    const float* b2    = (const float*)d_in[7];   // [1]
    float* out = (float*)d_out;

    const int* e_row = eidx;        // sources
    const int* e_col = eidx + EE;   // targets

    // workspace layout (floats):
    //   [0, NN)                       : deg -> dinv (in place)
    //   [F0, F0 + NN*CC)              : buf0 = h, then h1
    //   [F1, F1 + NN*CC)              : buf1 = agg, then h2
    const size_t F0 = 1 << 17;                 // 131072 floats, 512KB aligned
    const size_t F1 = F0 + (size_t)NN * CC;
    const size_t need_bytes = (F1 + (size_t)NN * CC) * sizeof(float);
    if (ws_size < need_bytes) return;  // workspace too small -> clean failure

    float* ws   = (float*)d_ws;
    float* dinv = ws;
    float* h    = ws + F0;   // buf0
    float* agg  = ws + F1;   // buf1
    float* h1   = h;         // overwrite h after aggregation
    float* h2   = agg;       // overwrite agg after bias+relu

    // 1. degrees
    k_init_deg<<<(NN + 255) / 256, 256, 0, stream>>>(dinv);
    k_count_deg<<<(EE + 255) / 256, 256, 0, stream>>>(e_col, dinv);
    k_rsqrt<<<(NN + 255) / 256, 256, 0, stream>>>(dinv);

    // 2. h = x @ W_gcn.T
    {
        dim3 grid(256 / 64, (NN + 63) / 64);
        k_gemm_nt<<<grid, 256, 0, stream>>>(x, W_gcn, nullptr, h, NN, CC, CC, 0);
    }

    // 3. aggregation
    {
        int n4 = NN * (CC / 4);
        k_self_loop<<<(n4 + 255) / 256, 256, 0, stream>>>(dinv, h, agg);
        k_edge_agg<<<(EE + 3) / 4, 256, 0, stream>>>(e_row, e_col, dinv, h, agg);
        k_bias_relu<<<(n4 + 255) / 256, 256, 0, stream>>>(agg, b_gcn, h1);
    }

    // 4. h2 = relu(h1 @ W1.T + b1)
    {
        dim3 grid(256 / 64, (NN + 63) / 64);
        k_gemm_nt<<<grid, 256, 0, stream>>>(h1, W1, b1, h2, NN, CC, CC, 1);
    }

    // 5. out = sigmoid(relu(h2 @ W2.T + b2))
    k_final<<<(NN + 3) / 4, 256, 0, stream>>>(h2, W2, b2, out);
}

// Round 3
// 1517.030 us; speedup vs baseline: 7.5926x; 7.5926x over previous
//
#include <hip/hip_runtime.h>
#include <math.h>

#define NN 100000
#define CC 256
#define EE 3200000

typedef unsigned short u16;

__device__ __forceinline__ float bf2f(u16 u) {
    return __uint_as_float(((unsigned int)u) << 16);
}
__device__ __forceinline__ u16 f2bf(float f) {
    unsigned int x = __float_as_uint(f);
    unsigned int r = (x + 0x7FFF + ((x >> 16) & 1)) >> 16;  // RNE
    return (u16)r;
}

// ---------------- CSR build ----------------

__global__ __launch_bounds__(256) void k_zero(int* __restrict__ cnt) {
    int i = blockIdx.x * 256 + threadIdx.x;
    if (i < NN) cnt[i] = 0;
}

__global__ __launch_bounds__(256) void k_count(const int* __restrict__ col,
                                               int* __restrict__ cnt) {
    int e = blockIdx.x * 256 + threadIdx.x;
    if (e < EE) atomicAdd(&cnt[col[e]], 1);
}

__global__ __launch_bounds__(256) void k_dinv(const int* __restrict__ cnt,
                                              float* __restrict__ dinv) {
    int i = blockIdx.x * 256 + threadIdx.x;
    if (i < NN) dinv[i] = rsqrtf((float)(cnt[i] + 1));  // +1 self loop
}

// single-block exclusive scan of cnt[0..NN) -> rowptr; cnt becomes cursor copy
__global__ __launch_bounds__(1024) void k_scan(int* __restrict__ cnt,
                                               int* __restrict__ rowptr) {
    __shared__ int sums[1024];
    const int t = threadIdx.x;
    const int chunk = (NN + 1023) / 1024;  // 98
    int beg = t * chunk;
    int end = beg + chunk; if (end > NN) end = NN;
    int s = 0;
    for (int i = beg; i < end && beg < NN; ++i) s += cnt[i];
    sums[t] = s;
    __syncthreads();
    for (int off = 1; off < 1024; off <<= 1) {
        int v = sums[t];
        int u = (t >= off) ? sums[t - off] : 0;
        __syncthreads();
        sums[t] = v + u;
        __syncthreads();
    }
    int run = (t == 0) ? 0 : sums[t - 1];  // exclusive prefix for this chunk
    if (beg < NN) {
        for (int i = beg; i < end; ++i) {
            int v = cnt[i];
            rowptr[i] = run;
            cnt[i] = run;  // cursor init
            run += v;
        }
    }
    if (t == 1023) rowptr[NN] = sums[1023];
}

__global__ __launch_bounds__(256) void k_scatter(const int* __restrict__ rowi,
                                                 const int* __restrict__ coli,
                                                 int* __restrict__ cursor,
                                                 int* __restrict__ srcs) {
    int e = blockIdx.x * 256 + threadIdx.x;
    if (e >= EE) return;
    int pos = atomicAdd(&cursor[coli[e]], 1);
    srcs[pos] = rowi[e];
}

// ---------------- GEMM1: h = x @ W.T  (A fp32, out bf16, no bias) ----------------
// A:[M,K] f32, B:[Nc,K] f32, out:[M,Nc] bf16. BM=BN=64, BK=32, 256 thr, 4x4/thread.

__global__ __launch_bounds__(256) void k_gemm_f32a(const float* __restrict__ A,
                                                   const float* __restrict__ B,
                                                   u16* __restrict__ Cout,
                                                   int M, int Nc, int K) {
    __shared__ float As[64][33];
    __shared__ float Bs[64][33];
    const int bm = blockIdx.y * 64;
    const int bn = blockIdx.x * 64;
    const int tid = threadIdx.x;
    const int tx = tid & 15;
    const int ty = tid >> 4;

    float acc[4][4] = {};

    for (int k0 = 0; k0 < K; k0 += 32) {
        #pragma unroll
        for (int r = 0; r < 2; ++r) {
            int idx = tid + r * 256;
            int row = idx >> 3;
            int c4  = (idx & 7) * 4;
            int grow = bm + row;
            float4 va = make_float4(0.f, 0.f, 0.f, 0.f);
            if (grow < M) va = *(const float4*)&A[(size_t)grow * K + k0 + c4];
            As[row][c4 + 0] = va.x; As[row][c4 + 1] = va.y;
            As[row][c4 + 2] = va.z; As[row][c4 + 3] = va.w;
            int brow = bn + row;
            float4 vb = make_float4(0.f, 0.f, 0.f, 0.f);
            if (brow < Nc) vb = *(const float4*)&B[(size_t)brow * K + k0 + c4];
            Bs[row][c4 + 0] = vb.x; Bs[row][c4 + 1] = vb.y;
            Bs[row][c4 + 2] = vb.z; Bs[row][c4 + 3] = vb.w;
        }
        __syncthreads();
        #pragma unroll
        for (int kk = 0; kk < 32; ++kk) {
            float a[4], b[4];
            #pragma unroll
            for (int r = 0; r < 4; ++r) a[r] = As[ty * 4 + r][kk];
            #pragma unroll
            for (int c = 0; c < 4; ++c) b[c] = Bs[tx * 4 + c][kk];
            #pragma unroll
            for (int r = 0; r < 4; ++r)
                #pragma unroll
                for (int c = 0; c < 4; ++c)
                    acc[r][c] = fmaf(a[r], b[c], acc[r][c]);
        }
        __syncthreads();
    }

    #pragma unroll
    for (int r = 0; r < 4; ++r) {
        int grow = bm + ty * 4 + r;
        if (grow >= M) continue;
        int gcol = bn + tx * 4;
        ushort4 o;
        o.x = f2bf(acc[r][0]); o.y = f2bf(acc[r][1]);
        o.z = f2bf(acc[r][2]); o.w = f2bf(acc[r][3]);
        *(ushort4*)&Cout[(size_t)grow * Nc + gcol] = o;
    }
}

// ---------------- GEMM2: h2 = relu(h1 @ W1.T + b1)  (A bf16, out bf16) ----------------

__global__ __launch_bounds__(256) void k_gemm_bf16a(const u16* __restrict__ A,
                                                    const float* __restrict__ B,
                                                    const float* __restrict__ bias,
                                                    u16* __restrict__ Cout,
                                                    int M, int Nc, int K) {
    __shared__ float As[64][33];
    __shared__ float Bs[64][33];
    const int bm = blockIdx.y * 64;
    const int bn = blockIdx.x * 64;
    const int tid = threadIdx.x;
    const int tx = tid & 15;
    const int ty = tid >> 4;

    float acc[4][4] = {};

    for (int k0 = 0; k0 < K; k0 += 32) {
        #pragma unroll
        for (int r = 0; r < 2; ++r) {
            int idx = tid + r * 256;
            int row = idx >> 3;
            int c4  = (idx & 7) * 4;
            int grow = bm + row;
            float a0 = 0.f, a1 = 0.f, a2 = 0.f, a3 = 0.f;
            if (grow < M) {
                ushort4 va = *(const ushort4*)&A[(size_t)grow * K + k0 + c4];
                a0 = bf2f(va.x); a1 = bf2f(va.y); a2 = bf2f(va.z); a3 = bf2f(va.w);
            }
            As[row][c4 + 0] = a0; As[row][c4 + 1] = a1;
            As[row][c4 + 2] = a2; As[row][c4 + 3] = a3;
            int brow = bn + row;
            float4 vb = make_float4(0.f, 0.f, 0.f, 0.f);
            if (brow < Nc) vb = *(const float4*)&B[(size_t)brow * K + k0 + c4];
            Bs[row][c4 + 0] = vb.x; Bs[row][c4 + 1] = vb.y;
            Bs[row][c4 + 2] = vb.z; Bs[row][c4 + 3] = vb.w;
        }
        __syncthreads();
        #pragma unroll
        for (int kk = 0; kk < 32; ++kk) {
            float a[4], b[4];
            #pragma unroll
            for (int r = 0; r < 4; ++r) a[r] = As[ty * 4 + r][kk];
            #pragma unroll
            for (int c = 0; c < 4; ++c) b[c] = Bs[tx * 4 + c][kk];
            #pragma unroll
            for (int r = 0; r < 4; ++r)
                #pragma unroll
                for (int c = 0; c < 4; ++c)
                    acc[r][c] = fmaf(a[r], b[c], acc[r][c]);
        }
        __syncthreads();
    }

    #pragma unroll
    for (int r = 0; r < 4; ++r) {
        int grow = bm + ty * 4 + r;
        if (grow >= M) continue;
        int gcol = bn + tx * 4;
        ushort4 o;
        #pragma unroll
        for (int c = 0; c < 4; ++c) {
            float v = acc[r][c] + bias[gcol + c];
            v = fmaxf(v, 0.f);
            ((u16*)&o)[c] = f2bf(v);
        }
        *(ushort4*)&Cout[(size_t)grow * Nc + gcol] = o;
    }
}

// ---------------- gather aggregation (fused self-loop + bias + relu) ----------------
// one wave per node; lane owns 4 channels (8B bf16 per edge read)

__global__ __launch_bounds__(256) void k_gather(const int* __restrict__ rowptr,
                                                const int* __restrict__ srcs,
                                                const float* __restrict__ dinv,
                                                const u16* __restrict__ hb,
                                                const float* __restrict__ b_gcn,
                                                u16* __restrict__ h1b) {
    int node = blockIdx.x * 4 + (threadIdx.x >> 6);
    if (node >= NN) return;
    int lane = threadIdx.x & 63;
    float di = dinv[node];

    // self loop: dinv^2 * h[node]
    ushort4 sv = ((const ushort4*)(hb + (size_t)node * CC))[lane];
    float w0 = di * di;
    float ax = bf2f(sv.x) * w0, ay = bf2f(sv.y) * w0,
          az = bf2f(sv.z) * w0, aw = bf2f(sv.w) * w0;

    int beg = rowptr[node], end = rowptr[node + 1];
    int e = beg;
    for (; e + 2 <= end; e += 2) {
        int s0 = srcs[e], s1 = srcs[e + 1];
        float w0_ = dinv[s0] * di;
        float w1_ = dinv[s1] * di;
        ushort4 a0 = ((const ushort4*)(hb + (size_t)s0 * CC))[lane];
        ushort4 a1 = ((const ushort4*)(hb + (size_t)s1 * CC))[lane];
        ax += bf2f(a0.x) * w0_; ay += bf2f(a0.y) * w0_;
        az += bf2f(a0.z) * w0_; aw += bf2f(a0.w) * w0_;
        ax += bf2f(a1.x) * w1_; ay += bf2f(a1.y) * w1_;
        az += bf2f(a1.z) * w1_; aw += bf2f(a1.w) * w1_;
    }
    if (e < end) {
        int s0 = srcs[e];
        float w0_ = dinv[s0] * di;
        ushort4 a0 = ((const ushort4*)(hb + (size_t)s0 * CC))[lane];
        ax += bf2f(a0.x) * w0_; ay += bf2f(a0.y) * w0_;
        az += bf2f(a0.z) * w0_; aw += bf2f(a0.w) * w0_;
    }

    float4 b = ((const float4*)b_gcn)[lane];
    ushort4 o;
    o.x = f2bf(fmaxf(ax + b.x, 0.f));
    o.y = f2bf(fmaxf(ay + b.y, 0.f));
    o.z = f2bf(fmaxf(az + b.z, 0.f));
    o.w = f2bf(fmaxf(aw + b.w, 0.f));
    ((ushort4*)(h1b + (size_t)node * CC))[lane] = o;
}

// ---------------- final layer: out = sigmoid(relu(h2 @ W2.T + b2)) ----------------

__global__ __launch_bounds__(256) void k_final(const u16* __restrict__ h2,
                                               const float* __restrict__ W2,
                                               const float* __restrict__ b2,
                                               float* __restrict__ out) {
    int wid = threadIdx.x >> 6;
    int lane = threadIdx.x & 63;
    int rowi = blockIdx.x * 4 + wid;
    if (rowi >= NN) return;
    ushort4 a = ((const ushort4*)(h2 + (size_t)rowi * CC))[lane];
    float4 w = ((const float4*)W2)[lane];
    float s = bf2f(a.x) * w.x + bf2f(a.y) * w.y + bf2f(a.z) * w.z + bf2f(a.w) * w.w;
    #pragma unroll
    for (int off = 32; off >= 1; off >>= 1) s += __shfl_down(s, off, 64);
    if (lane == 0) {
        float z = s + b2[0];
        z = fmaxf(z, 0.f);
        out[rowi] = 1.0f / (1.0f + expf(-z));
    }
}

// ---------------- launcher ----------------

extern "C" void kernel_launch(void* const* d_in, const int* in_sizes, int n_in,
                              void* d_out, int out_size, void* d_ws, size_t ws_size,
                              hipStream_t stream) {
    const float* x     = (const float*)d_in[0];
    const int*   eidx  = (const int*)d_in[1];
    const float* W_gcn = (const float*)d_in[2];
    const float* b_gcn = (const float*)d_in[3];
    const float* W1    = (const float*)d_in[4];
    const float* b1    = (const float*)d_in[5];
    const float* W2    = (const float*)d_in[6];
    const float* b2    = (const float*)d_in[7];
    float* out = (float*)d_out;

    const int* e_row = eidx;        // sources
    const int* e_col = eidx + EE;   // targets

    // workspace layout (bytes):
    char* ws = (char*)d_ws;
    const size_t MB = 1024 * 1024;
    float* dinv   = (float*)(ws + 0);               // 0.4 MB
    int*   cnt    = (int*)  (ws + 1 * MB);          // 0.4 MB (becomes cursor)
    int*   rowptr = (int*)  (ws + 2 * MB);          // 0.4 MB
    int*   srcs   = (int*)  (ws + 3 * MB);          // 12.8 MB
    u16*   hb     = (u16*)  (ws + 16 * MB);         // 51.2 MB
    u16*   h1b    = (u16*)  (ws + 68 * MB);         // 51.2 MB
    u16*   h2b    = (u16*)  (ws + 120 * MB);        // 51.2 MB
    const size_t need = 172 * MB;
    if (ws_size < need) return;

    // 1. CSR build + dinv
    k_zero<<<(NN + 255) / 256, 256, 0, stream>>>(cnt);
    k_count<<<(EE + 255) / 256, 256, 0, stream>>>(e_col, cnt);
    k_dinv<<<(NN + 255) / 256, 256, 0, stream>>>(cnt, dinv);
    k_scan<<<1, 1024, 0, stream>>>(cnt, rowptr);
    k_scatter<<<(EE + 255) / 256, 256, 0, stream>>>(e_row, e_col, cnt, srcs);

    // 2. h = x @ W_gcn.T  (bf16 out)
    {
        dim3 grid(CC / 64, (NN + 63) / 64);
        k_gemm_f32a<<<grid, 256, 0, stream>>>(x, W_gcn, hb, NN, CC, CC);
    }

    // 3. h1 = relu(aggregate + b_gcn)  (gather over CSR)
    k_gather<<<(NN + 3) / 4, 256, 0, stream>>>(rowptr, srcs, dinv, hb, b_gcn, h1b);

    // 4. h2 = relu(h1 @ W1.T + b1)
    {
        dim3 grid(CC / 64, (NN + 63) / 64);
        k_gemm_bf16a<<<grid, 256, 0, stream>>>(h1b, W1, b1, h2b, NN, CC, CC);
    }

    // 5. out = sigmoid(relu(h2 @ W2.T + b2))
    k_final<<<(NN + 3) / 4, 256, 0, stream>>>(h2b, W2, b2, out);
}

// Round 4
// 1142.271 us; speedup vs baseline: 10.0836x; 1.3281x over previous
//
#include <hip/hip_runtime.h>
#include <math.h>

#define NN 100000
#define CC 256
#define EE 3200000

typedef unsigned short u16;
typedef __attribute__((ext_vector_type(4))) float f32x4;
typedef __attribute__((ext_vector_type(8))) short bf16x8;

__device__ __forceinline__ float bf2f(u16 u) {
    return __uint_as_float(((unsigned int)u) << 16);
}
__device__ __forceinline__ u16 f2bf(float f) {
    unsigned int x = __float_as_uint(f);
    unsigned int r = (x + 0x7FFF + ((x >> 16) & 1)) >> 16;  // RNE
    return (u16)r;
}

#define GLOAD_LDS16(gsrc, ldst)                                                        \
    __builtin_amdgcn_global_load_lds((const __attribute__((address_space(1))) void*)(gsrc), \
                                     (__attribute__((address_space(3))) void*)(ldst), 16, 0, 0)

// ---------------- dtype conversion ----------------

__global__ __launch_bounds__(256) void k_cvt(const float* __restrict__ in,
                                             u16* __restrict__ out, int n4) {
    int i = blockIdx.x * 256 + threadIdx.x;
    if (i >= n4) return;
    float4 v = ((const float4*)in)[i];
    ushort4 o;
    o.x = f2bf(v.x); o.y = f2bf(v.y); o.z = f2bf(v.z); o.w = f2bf(v.w);
    ((ushort4*)out)[i] = o;
}

// ---------------- CSR build ----------------

__global__ __launch_bounds__(256) void k_zero(int* __restrict__ cnt) {
    int i = blockIdx.x * 256 + threadIdx.x;
    if (i < NN) cnt[i] = 0;
}

__global__ __launch_bounds__(256) void k_count(const int* __restrict__ col,
                                               int* __restrict__ cnt) {
    int e = blockIdx.x * 256 + threadIdx.x;
    if (e < EE) atomicAdd(&cnt[col[e]], 1);
}

__global__ __launch_bounds__(256) void k_dinv(const int* __restrict__ cnt,
                                              float* __restrict__ dinv) {
    int i = blockIdx.x * 256 + threadIdx.x;
    if (i < NN) dinv[i] = rsqrtf((float)(cnt[i] + 1));  // +1 self loop
}

// single-block exclusive scan of cnt[0..NN) -> rowptr; cnt becomes cursor copy
__global__ __launch_bounds__(1024) void k_scan(int* __restrict__ cnt,
                                               int* __restrict__ rowptr) {
    __shared__ int sums[1024];
    const int t = threadIdx.x;
    const int chunk = (NN + 1023) / 1024;  // 98
    int beg = t * chunk;
    int end = beg + chunk; if (end > NN) end = NN;
    int s = 0;
    for (int i = beg; i < end && beg < NN; ++i) s += cnt[i];
    sums[t] = s;
    __syncthreads();
    for (int off = 1; off < 1024; off <<= 1) {
        int v = sums[t];
        int u = (t >= off) ? sums[t - off] : 0;
        __syncthreads();
        sums[t] = v + u;
        __syncthreads();
    }
    int run = (t == 0) ? 0 : sums[t - 1];
    if (beg < NN) {
        for (int i = beg; i < end; ++i) {
            int v = cnt[i];
            rowptr[i] = run;
            cnt[i] = run;  // cursor init
            run += v;
        }
    }
    if (t == 1023) rowptr[NN] = sums[1023];
}

__global__ __launch_bounds__(256) void k_scatter(const int* __restrict__ rowi,
                                                 const int* __restrict__ coli,
                                                 int* __restrict__ cursor,
                                                 int* __restrict__ srcs) {
    int e = blockIdx.x * 256 + threadIdx.x;
    if (e >= EE) return;
    int pos = atomicAdd(&cursor[coli[e]], 1);
    srcs[pos] = rowi[e];
}

// ---------------- bf16 MFMA NT-GEMM: C = A @ B^T (+bias, relu) ----------------
// A: [M][256] bf16 row-major. B: [256][256] bf16 row-major (weights, N x K).
// out: [M][256] bf16. Tile BM=BN=128, BK=32, 4 waves, each wave 64x64 (4x4 frags).
// LDS tiles hold rows of 32 bf16 (64B = 4 x 16B chunks); chunk index is
// XOR-swizzled with (row>>1)&3 to break the stride-64B bank conflict.
// Swizzle applied BOTH on the global_load_lds source and the ds_read address.

__global__ __launch_bounds__(256) void k_gemm_mfma(const u16* __restrict__ A,
                                                   const u16* __restrict__ B,
                                                   const float* __restrict__ bias,
                                                   u16* __restrict__ Cout,
                                                   int M, int relu) {
    __shared__ __align__(16) u16 As[128 * 32];  // 8KB
    __shared__ __align__(16) u16 Bs[128 * 32];  // 8KB
    const int tid = threadIdx.x;
    const int lane = tid & 63;
    const int wave = tid >> 6;
    const int wr = wave >> 1, wc = wave & 1;  // wave owns 64x64 at (wr*64, wc*64)
    const int bm = blockIdx.y * 128;
    const int bn = blockIdx.x * 128;

    f32x4 acc[4][4] = {};  // [m][n]

    for (int k0 = 0; k0 < 256; k0 += 32) {
        // stage A and B tiles: 512 x 16B chunks each, 2 per thread per tile.
        // physical chunk g -> row g>>2, physical slot g&3, logical slot = phys ^ ((row>>1)&3)
        #pragma unroll
        for (int i = 0; i < 2; ++i) {
            int g = tid + i * 256;
            int row = g >> 2;
            int lc = (g & 3) ^ ((row >> 1) & 3);
            int ga = bm + row; if (ga >= M) ga = M - 1;  // clamp (junk rows never stored)
            GLOAD_LDS16(A + (size_t)ga * 256 + k0 + lc * 8, (char*)As + (size_t)g * 16);
            int gb = bn + row;  // N=256 exact, no clamp needed
            GLOAD_LDS16(B + (size_t)gb * 256 + k0 + lc * 8, (char*)Bs + (size_t)g * 16);
        }
        __syncthreads();

        bf16x8 af[4], bfr[4];
        #pragma unroll
        for (int m = 0; m < 4; ++m) {
            int r = wr * 64 + m * 16 + (lane & 15);
            int ch = (lane >> 4) ^ ((r >> 1) & 3);
            af[m] = *(const bf16x8*)&As[r * 32 + ch * 8];
        }
        #pragma unroll
        for (int n = 0; n < 4; ++n) {
            int r = wc * 64 + n * 16 + (lane & 15);
            int ch = (lane >> 4) ^ ((r >> 1) & 3);
            bfr[n] = *(const bf16x8*)&Bs[r * 32 + ch * 8];
        }
        #pragma unroll
        for (int m = 0; m < 4; ++m)
            #pragma unroll
            for (int n = 0; n < 4; ++n)
                acc[m][n] = __builtin_amdgcn_mfma_f32_16x16x32_bf16(af[m], bfr[n],
                                                                    acc[m][n], 0, 0, 0);
        __syncthreads();
    }

    // epilogue: D element (reg j): row = (lane>>4)*4 + j, col = lane&15  [m89 layout]
    #pragma unroll
    for (int m = 0; m < 4; ++m) {
        int grow_base = bm + wr * 64 + m * 16 + (lane >> 4) * 4;
        #pragma unroll
        for (int n = 0; n < 4; ++n) {
            int gcol = bn + wc * 64 + n * 16 + (lane & 15);
            float bv = bias ? bias[gcol] : 0.f;
            #pragma unroll
            for (int j = 0; j < 4; ++j) {
                int grow = grow_base + j;
                if (grow < M) {
                    float v = acc[m][n][j] + bv;
                    if (relu) v = fmaxf(v, 0.f);
                    Cout[(size_t)grow * 256 + gcol] = f2bf(v);
                }
            }
        }
    }
}

// ---------------- gather aggregation (fused self-loop + bias + relu) ----------------

__global__ __launch_bounds__(256) void k_gather(const int* __restrict__ rowptr,
                                                const int* __restrict__ srcs,
                                                const float* __restrict__ dinv,
                                                const u16* __restrict__ hb,
                                                const float* __restrict__ b_gcn,
                                                u16* __restrict__ h1b) {
    int node = blockIdx.x * 4 + (threadIdx.x >> 6);
    if (node >= NN) return;
    int lane = threadIdx.x & 63;
    float di = dinv[node];

    ushort4 sv = ((const ushort4*)(hb + (size_t)node * CC))[lane];
    float w0 = di * di;
    float ax = bf2f(sv.x) * w0, ay = bf2f(sv.y) * w0,
          az = bf2f(sv.z) * w0, aw = bf2f(sv.w) * w0;

    int beg = rowptr[node], end = rowptr[node + 1];
    int e = beg;
    for (; e + 2 <= end; e += 2) {
        int s0 = srcs[e], s1 = srcs[e + 1];
        float wa = dinv[s0] * di;
        float wb = dinv[s1] * di;
        ushort4 a0 = ((const ushort4*)(hb + (size_t)s0 * CC))[lane];
        ushort4 a1 = ((const ushort4*)(hb + (size_t)s1 * CC))[lane];
        ax += bf2f(a0.x) * wa; ay += bf2f(a0.y) * wa;
        az += bf2f(a0.z) * wa; aw += bf2f(a0.w) * wa;
        ax += bf2f(a1.x) * wb; ay += bf2f(a1.y) * wb;
        az += bf2f(a1.z) * wb; aw += bf2f(a1.w) * wb;
    }
    if (e < end) {
        int s0 = srcs[e];
        float wa = dinv[s0] * di;
        ushort4 a0 = ((const ushort4*)(hb + (size_t)s0 * CC))[lane];
        ax += bf2f(a0.x) * wa; ay += bf2f(a0.y) * wa;
        az += bf2f(a0.z) * wa; aw += bf2f(a0.w) * wa;
    }

    float4 b = ((const float4*)b_gcn)[lane];
    ushort4 o;
    o.x = f2bf(fmaxf(ax + b.x, 0.f));
    o.y = f2bf(fmaxf(ay + b.y, 0.f));
    o.z = f2bf(fmaxf(az + b.z, 0.f));
    o.w = f2bf(fmaxf(aw + b.w, 0.f));
    ((ushort4*)(h1b + (size_t)node * CC))[lane] = o;
}

// ---------------- final layer: out = sigmoid(relu(h2 @ W2.T + b2)) ----------------

__global__ __launch_bounds__(256) void k_final(const u16* __restrict__ h2,
                                               const float* __restrict__ W2,
                                               const float* __restrict__ b2,
                                               float* __restrict__ out) {
    int wid = threadIdx.x >> 6;
    int lane = threadIdx.x & 63;
    int rowi = blockIdx.x * 4 + wid;
    if (rowi >= NN) return;
    ushort4 a = ((const ushort4*)(h2 + (size_t)rowi * CC))[lane];
    float4 w = ((const float4*)W2)[lane];
    float s = bf2f(a.x) * w.x + bf2f(a.y) * w.y + bf2f(a.z) * w.z + bf2f(a.w) * w.w;
    #pragma unroll
    for (int off = 32; off >= 1; off >>= 1) s += __shfl_down(s, off, 64);
    if (lane == 0) {
        float z = s + b2[0];
        z = fmaxf(z, 0.f);
        out[rowi] = 1.0f / (1.0f + expf(-z));
    }
}

// ---------------- launcher ----------------

extern "C" void kernel_launch(void* const* d_in, const int* in_sizes, int n_in,
                              void* d_out, int out_size, void* d_ws, size_t ws_size,
                              hipStream_t stream) {
    const float* x     = (const float*)d_in[0];
    const int*   eidx  = (const int*)d_in[1];
    const float* W_gcn = (const float*)d_in[2];
    const float* b_gcn = (const float*)d_in[3];
    const float* W1    = (const float*)d_in[4];
    const float* b1    = (const float*)d_in[5];
    const float* W2    = (const float*)d_in[6];
    const float* b2    = (const float*)d_in[7];
    float* out = (float*)d_out;

    const int* e_row = eidx;        // sources
    const int* e_col = eidx + EE;   // targets

    // workspace layout (bytes):
    char* ws = (char*)d_ws;
    const size_t MB = 1024 * 1024;
    float* dinv   = (float*)(ws + 0);            // 0.4 MB
    int*   cnt    = (int*)  (ws + 1 * MB);       // 0.4 MB (becomes cursor)
    int*   rowptr = (int*)  (ws + 2 * MB);       // 0.4 MB
    int*   srcs   = (int*)  (ws + 3 * MB);       // 12.8 MB
    u16*   WgB    = (u16*)  (ws + 16 * MB);      // 128 KB
    u16*   W1B    = (u16*)  (ws + 16 * MB + 256 * 1024);  // 128 KB
    u16*   slotA  = (u16*)  (ws + 18 * MB);      // 51.2 MB: xb, then h1b
    u16*   slotB  = (u16*)  (ws + 70 * MB);      // 51.2 MB: hb, then h2b
    const size_t need = 122 * MB;
    if (ws_size < need) return;

    u16* xb  = slotA;
    u16* hb  = slotB;
    u16* h1b = slotA;   // overwrites xb (dead after GEMM1)
    u16* h2b = slotB;   // overwrites hb (dead after gather)

    // 1. CSR build + dinv
    k_zero<<<(NN + 255) / 256, 256, 0, stream>>>(cnt);
    k_count<<<(EE + 255) / 256, 256, 0, stream>>>(e_col, cnt);
    k_dinv<<<(NN + 255) / 256, 256, 0, stream>>>(cnt, dinv);
    k_scan<<<1, 1024, 0, stream>>>(cnt, rowptr);
    k_scatter<<<(EE + 255) / 256, 256, 0, stream>>>(e_row, e_col, cnt, srcs);

    // 2. dtype conversions
    k_cvt<<<(NN * CC / 4 + 255) / 256, 256, 0, stream>>>(x, xb, NN * CC / 4);
    k_cvt<<<(CC * CC / 4 + 255) / 256, 256, 0, stream>>>(W_gcn, WgB, CC * CC / 4);
    k_cvt<<<(CC * CC / 4 + 255) / 256, 256, 0, stream>>>(W1, W1B, CC * CC / 4);

    // 3. h = x @ W_gcn.T  (MFMA, bf16)
    {
        dim3 grid(2, (NN + 127) / 128);
        k_gemm_mfma<<<grid, 256, 0, stream>>>(xb, WgB, nullptr, hb, NN, 0);
    }

    // 4. h1 = relu(aggregate + b_gcn)  (gather over CSR)
    k_gather<<<(NN + 3) / 4, 256, 0, stream>>>(rowptr, srcs, dinv, hb, b_gcn, h1b);

    // 5. h2 = relu(h1 @ W1.T + b1)  (MFMA, bf16)
    {
        dim3 grid(2, (NN + 127) / 128);
        k_gemm_mfma<<<grid, 256, 0, stream>>>(h1b, W1B, b1, h2b, NN, 1);
    }

    // 6. out = sigmoid(relu(h2 @ W2.T + b2))
    k_final<<<(NN + 3) / 4, 256, 0, stream>>>(h2b, W2, b2, out);
}